// Round 2
// baseline (901.486 us; speedup 1.0000x reference)
//
#include <hip/hip_runtime.h>

#define NB 256            // blocks (1 per CU)
#define BT 512            // threads per block (8 waves)
#define MSTEPS 8
// Fixed problem shape: L = 500000.
#define CHUNK 1954        // ceil(500000 / NB) rows per block
#define REGT 13           // register-resident rows per quad (13*128 = 1664 rows)
#define REGL (REGT * 128)
#define LDSROWS (CHUNK - REGL)   // 290 rows resident in LDS
#define LDSTRIDE 36       // 36 floats = 144 B padded row

typedef float v8f __attribute__((ext_vector_type(8)));
typedef float v4f __attribute__((ext_vector_type(4)));

struct PParams {
  const float* candidate;
  const float* z_past;
  const float* q_w; const float* q_b;
  const float* k_w; const float* k_b;
  const float* v_w; const float* v_b;
  const float* o_w; const float* o_b;
  const float* rel_bias;
  const float* coupling;
  const float* norm_scale;
  float* out;
  float* ws;   // [0..15] uint barrier state (memset to 0 each launch); [16..] 2*132*NB partials
  int L;
};

__device__ __forceinline__ float mish_f(float x) {
  float sp = fmaxf(x, 0.0f) + log1pf(expf(-fabsf(x)));
  return x * tanhf(sp);
}

// Recompute q projection, folded score vectors a_h (pre-scaled by inv_sqrt_d=0.5),
// and the l<64 relative-bias delta table, from the current state sZ.
// Must be called by ALL threads of the block (contains barriers).
__device__ void compute_qar(const PParams& p, int tid,
                            float* sZ, float* sQ, float* sA, float* sRel) {
  if (tid < 32) {
    float acc = p.q_b[tid];
    const float* row = p.q_w + tid * 32;
    #pragma unroll
    for (int c = 0; c < 32; ++c) acc = fmaf(row[c], sZ[c], acc);
    sQ[tid] = acc;
  }
  __syncthreads();
  if (tid < 128) {
    int h = tid >> 5, c = tid & 31;
    float acc = 0.f;
    #pragma unroll
    for (int jj = 0; jj < 8; ++jj)
      acc = fmaf(sQ[8 * h + jj], p.k_w[(8 * h + jj) * 32 + c], acc);
    sA[tid] = 0.5f * acc;               // fold inv_sqrt_d
  }
  if (tid >= 256) {
    // rel-bias delta vs the saturated idx=128 entry (constant part cancels in softmax)
    int t = tid - 256;
    int l = t >> 2, h = t & 3;
    float acc = 0.f;
    #pragma unroll
    for (int jj = 0; jj < 8; ++jj) {
      int jidx = 8 * h + jj;
      acc = fmaf(sQ[jidx],
                 p.rel_bias[(l + 64) * 32 + jidx] - p.rel_bias[128 * 32 + jidx],
                 acc);
    }
    sRel[t] = 0.5f * acc;
  }
  __syncthreads();
}

// Minimal grid barrier: one release-add per block, relaxed spin on a flag,
// agent fences at the edges. Counters zeroed by hipMemsetAsync each launch.
__device__ __forceinline__ void grid_barrier(float* wsf, int iter, int tid) {
  unsigned* sync = reinterpret_cast<unsigned*>(wsf);
  __syncthreads();
  __threadfence();                     // release block's partial-table stores
  if (tid == 0) {
    unsigned* cnt = sync + 2 * iter;
    unsigned* flg = sync + 2 * iter + 1;
    unsigned old = __hip_atomic_fetch_add(cnt, 1u, __ATOMIC_RELEASE,
                                          __HIP_MEMORY_SCOPE_AGENT);
    if (old == (unsigned)(NB - 1)) {
      __hip_atomic_store(flg, 1u, __ATOMIC_RELEASE, __HIP_MEMORY_SCOPE_AGENT);
    } else {
      while (__hip_atomic_load(flg, __ATOMIC_RELAXED,
                               __HIP_MEMORY_SCOPE_AGENT) == 0u)
        __builtin_amdgcn_s_sleep(4);   // ~256-cycle poll granularity
    }
  }
  __syncthreads();
  __threadfence();                     // acquire: invalidate stale caches before reads
}

// One l-row contribution. Everything is SSA vectors / constant-indexed —
// nothing here may become addressable (round-1 lesson: scratch spill).
__device__ __forceinline__ void trip_body(const v8f (&A)[4], v8f zv,
                                          const float* sRel, bool dorel, int relrow,
                                          v8f (&S)[4], v4f& Zc) {
  float d0 = 0.f, d1 = 0.f, d2 = 0.f, d3 = 0.f;
  #pragma unroll
  for (int k = 0; k < 8; ++k) {
    d0 = fmaf(A[0][k], zv[k], d0);
    d1 = fmaf(A[1][k], zv[k], d1);
    d2 = fmaf(A[2][k], zv[k], d2);
    d3 = fmaf(A[3][k], zv[k], d3);
  }
  d0 += __shfl_xor(d0, 1); d0 += __shfl_xor(d0, 2);
  d1 += __shfl_xor(d1, 1); d1 += __shfl_xor(d1, 2);
  d2 += __shfl_xor(d2, 1); d2 += __shfl_xor(d2, 2);
  d3 += __shfl_xor(d3, 1); d3 += __shfl_xor(d3, 2);
  if (dorel) {
    const float4 r = reinterpret_cast<const float4*>(sRel)[relrow];
    d0 += r.x; d1 += r.y; d2 += r.z; d3 += r.w;
  }
  float w0 = __expf(d0), w1 = __expf(d1), w2 = __expf(d2), w3 = __expf(d3);
  Zc[0] += w0; Zc[1] += w1; Zc[2] += w2; Zc[3] += w3;
  S[0] += zv * w0;
  S[1] += zv * w1;
  S[2] += zv * w2;
  S[3] += zv * w3;
}

__global__ __launch_bounds__(BT, 2)
void photonic_kernel(PParams p) {
  __shared__ float sZ[32];
  __shared__ float sQ[32];
  __shared__ float sOutV[32];
  __shared__ float sZn[32];
  __shared__ __align__(32) float sA[128];     // a[h][c]
  __shared__ __align__(16) float sRel[256];   // relT[l][h], l<64
  __shared__ float sRed[BT / 64][4][36];      // per-wave reduced (S[4][8] + Z[4]) per quarter
  __shared__ float sSS[128];                  // global-reduced S[h][c]
  __shared__ float sSZ[4];                    // global-reduced Z[h]
  __shared__ __align__(16) float sZp[LDSROWS * LDSTRIDE];  // LDS-resident z rows (padded)

  const int tid  = threadIdx.x;
  const int b    = blockIdx.x;
  const int j    = tid & 3;        // quarter (owns columns [8j, 8j+8))
  const int quad = tid >> 2;       // 0..127
  const int wave = tid >> 6;
  const int lane = tid & 63;

  const int chunk0 = b * CHUNK;
  const int clen   = min(CHUNK, p.L - chunk0);          // 1954, last block 1730
  const int ldsl   = min(clen - REGL, (int)LDSROWS);    // 290, last block 66

  // init state z = candidate (real-interleaved flat 32)
  if (tid < 32) sZ[tid] = p.candidate[tid];
  __syncthreads();
  compute_qar(p, tid, sZ, sQ, sA, sRel);

  // Register-resident slice of z_past: rows chunk0 + quad + t*128, t < REGT.
  // Held as ext-vector SSA values so they can NEVER be spilled via addressability.
  v8f zr0, zr1, zr2, zr3, zr4, zr5, zr6, zr7, zr8, zr9, zr10, zr11, zr12;

  for (int iter = 0; iter < MSTEPS; ++iter) {
    // stage my quarter of a[h][*] into registers
    v8f A[4];
    #pragma unroll
    for (int h = 0; h < 4; ++h)
      A[h] = *reinterpret_cast<const v8f*>(sA + h * 32 + j * 8);

    v8f S[4];
    #pragma unroll
    for (int h = 0; h < 4; ++h) S[h] = 0.f;
    v4f Zc = 0.f;

    if (iter == 0) {
      // ---- first pass: load from HBM, populate registers + LDS, and compute ----
      #define LOADROW(t, dst)                                                   \
        {                                                                       \
          dst = *reinterpret_cast<const v8f*>(                                  \
              p.z_past + (size_t)(chunk0 + quad + ((t) << 7)) * 32 + j * 8);    \
          trip_body(A, dst, sRel, (b == 0) && ((t) == 0) && (quad < 64), quad,  \
                    S, Zc);                                                     \
        }
      LOADROW(0, zr0)  LOADROW(1, zr1)  LOADROW(2, zr2)  LOADROW(3, zr3)
      LOADROW(4, zr4)  LOADROW(5, zr5)  LOADROW(6, zr6)  LOADROW(7, zr7)
      LOADROW(8, zr8)  LOADROW(9, zr9)  LOADROW(10, zr10) LOADROW(11, zr11)
      LOADROW(12, zr12)
      #undef LOADROW
      #pragma unroll
      for (int t = 0; t < 3; ++t) {
        int li = quad + (t << 7);
        if (li < ldsl) {
          v8f zv = *reinterpret_cast<const v8f*>(
              p.z_past + (size_t)(chunk0 + REGL + li) * 32 + j * 8);
          float* dst = sZp + li * LDSTRIDE + j * 8;
          *reinterpret_cast<v4f*>(dst)     = __builtin_shufflevector(zv, zv, 0, 1, 2, 3);
          *reinterpret_cast<v4f*>(dst + 4) = __builtin_shufflevector(zv, zv, 4, 5, 6, 7);
          trip_body(A, zv, sRel, false, 0, S, Zc);
        }
      }
    } else {
      // ---- steady state: zero global traffic; registers + LDS only ----
      #define COMPROW(t, src)                                                   \
        trip_body(A, src, sRel, (b == 0) && ((t) == 0) && (quad < 64), quad, S, \
                  Zc);
      COMPROW(0, zr0)  COMPROW(1, zr1)  COMPROW(2, zr2)  COMPROW(3, zr3)
      COMPROW(4, zr4)  COMPROW(5, zr5)  COMPROW(6, zr6)  COMPROW(7, zr7)
      COMPROW(8, zr8)  COMPROW(9, zr9)  COMPROW(10, zr10) COMPROW(11, zr11)
      COMPROW(12, zr12)
      #undef COMPROW
      #pragma unroll
      for (int t = 0; t < 3; ++t) {
        int li = quad + (t << 7);
        if (li < ldsl) {
          const float* src = sZp + li * LDSTRIDE + j * 8;
          v4f a4 = *reinterpret_cast<const v4f*>(src);
          v4f b4 = *reinterpret_cast<const v4f*>(src + 4);
          v8f zv = __builtin_shufflevector(a4, b4, 0, 1, 2, 3, 4, 5, 6, 7);
          trip_body(A, zv, sRel, false, 0, S, Zc);
        }
      }
    }

    // reduce across the 16 quads of each wave (lane%4 == quarter is preserved)
    #pragma unroll
    for (int m = 4; m <= 32; m <<= 1) {
      #pragma unroll
      for (int h = 0; h < 4; ++h) {
        #pragma unroll
        for (int k = 0; k < 8; ++k) S[h][k] += __shfl_xor(S[h][k], m);
        Zc[h] += __shfl_xor(Zc[h], m);
      }
    }
    if ((lane >> 2) == 0) {  // lanes 0..3: lane == quarter j
      #pragma unroll
      for (int h = 0; h < 4; ++h) {
        #pragma unroll
        for (int k = 0; k < 8; ++k) sRed[wave][lane][h * 8 + k] = S[h][k];
        sRed[wave][lane][32 + h] = Zc[h];
      }
    }
    __syncthreads();

    // per-block partials -> global, component-major [comp][block] for coalesced reduce
    float* part = p.ws + 16 + (iter & 1) * (132 * NB);
    if (tid < 132) {
      float acc = 0.f;
      if (tid < 128) {
        int h = tid >> 5, c = tid & 31;
        int jj = c >> 3, k = c & 7;
        #pragma unroll
        for (int w2 = 0; w2 < BT / 64; ++w2) acc += sRed[w2][jj][h * 8 + k];
        part[(h * 33 + c) * NB + b] = acc;
      } else {
        int h = tid - 128;
        #pragma unroll
        for (int w2 = 0; w2 < BT / 64; ++w2) acc += sRed[w2][0][32 + h];
        part[(h * 33 + 32) * NB + b] = acc;
      }
    }

    grid_barrier(p.ws, iter, tid);

    // every block redundantly reduces all partials (135 KB, L2/L3-resident)
    if (tid < 132) {
      const float4* pp = reinterpret_cast<const float4*>(part + tid * NB);
      float acc = 0.f;
      for (int i = 0; i < NB / 4; ++i) {
        float4 v4 = pp[i];
        acc += (v4.x + v4.y) + (v4.z + v4.w);
      }
      int h = tid / 33, k = tid % 33;
      if (k < 32) sSS[h * 32 + k] = acc; else sSZ[h] = acc;
    }
    __syncthreads();

    // out_flat[j'] = v_w[j',:] @ (S_h / Z_h) + v_b[j']   (h = j'>>3)
    if (tid < 32) {
      int h = tid >> 3;
      float acc = 0.f;
      const float* row = p.v_w + tid * 32;
      #pragma unroll
      for (int c = 0; c < 32; ++c) acc = fmaf(row[c], sSS[h * 32 + c], acc);
      sOutV[tid] = acc / sSZ[h] + p.v_b[tid];
    }
    __syncthreads();
    // mod = o_w @ out + o_b ; z += coupling*mod ; mish
    if (tid < 32) {
      float acc = p.o_b[tid];
      const float* row = p.o_w + tid * 32;
      #pragma unroll
      for (int c = 0; c < 32; ++c) acc = fmaf(row[c], sOutV[c], acc);
      float zv2 = sZ[tid] + p.coupling[0] * acc;
      sZn[tid] = mish_f(zv2);
    }
    __syncthreads();
    // layer-norm over the 16 real / 16 imag components separately
    if (tid < 32) {
      int par = tid & 1;
      float m = 0.f;
      #pragma unroll
      for (int e = 0; e < 16; ++e) m += sZn[2 * e + par];
      m *= (1.f / 16.f);
      float v = 0.f;
      #pragma unroll
      for (int e = 0; e < 16; ++e) { float dd = sZn[2 * e + par] - m; v = fmaf(dd, dd, v); }
      v *= (1.f / 16.f);
      sZ[tid] = (sZn[tid] - m) * rsqrtf(v + 1e-5f) * p.norm_scale[0];
    }
    __syncthreads();

    if (iter != MSTEPS - 1) {
      compute_qar(p, tid, sZ, sQ, sA, sRel);
    } else {
      if (b == 0 && tid < 32) p.out[tid] = sZ[tid];
    }
  }
}

extern "C" void kernel_launch(void* const* d_in, const int* in_sizes, int n_in,
                              void* d_out, int out_size, void* d_ws, size_t ws_size,
                              hipStream_t stream) {
  PParams p;
  p.candidate  = (const float*)d_in[0];
  p.z_past     = (const float*)d_in[1];
  p.q_w = (const float*)d_in[2];  p.q_b = (const float*)d_in[3];
  p.k_w = (const float*)d_in[4];  p.k_b = (const float*)d_in[5];
  p.v_w = (const float*)d_in[6];  p.v_b = (const float*)d_in[7];
  p.o_w = (const float*)d_in[8];  p.o_b = (const float*)d_in[9];
  p.rel_bias   = (const float*)d_in[10];
  p.coupling   = (const float*)d_in[11];
  p.norm_scale = (const float*)d_in[12];
  p.out = (float*)d_out;
  p.ws  = (float*)d_ws;
  p.L   = in_sizes[1] / 32;

  // zero the 16 barrier words (captured as a graph node -> re-zeroed every replay)
  hipMemsetAsync(d_ws, 0, 64, stream);

  void* args[] = { &p };
  hipLaunchCooperativeKernel((const void*)photonic_kernel,
                             dim3(NB), dim3(BT), args, 0, stream);
}

// Round 3
// 889.026 us; speedup vs baseline: 1.0140x; 1.0140x over previous
//
#include <hip/hip_runtime.h>

#define NB 256            // blocks (1 per CU)
#define BT 512            // threads per block (8 waves)
#define MSTEPS 8
// Fixed problem shape: L = 500000.
#define CHUNK 1954        // ceil(500000 / NB) rows per block
#define REGT 13           // register-resident rows per quad (13*128 = 1664 rows)
#define REGL (REGT * 128)
#define LDSROWS (CHUNK - REGL)   // 290 rows resident in LDS
#define LDSTRIDE 36       // 36 floats = 144 B padded row

typedef float v8f __attribute__((ext_vector_type(8)));
typedef float v4f __attribute__((ext_vector_type(4)));

struct PParams {
  const float* candidate;
  const float* z_past;
  const float* q_w; const float* q_b;
  const float* k_w; const float* k_b;
  const float* v_w; const float* v_b;
  const float* o_w; const float* o_b;
  const float* rel_bias;
  const float* coupling;
  const float* norm_scale;
  float* out;
  float* ws;   // [0..15] uint barrier state (memset to 0 each launch); [16..] 2*132*NB partials
  int L;
};

__device__ __forceinline__ float mish_f(float x) {
  float sp = fmaxf(x, 0.0f) + log1pf(expf(-fabsf(x)));
  return x * tanhf(sp);
}

// Recompute q projection, folded score vectors a_h (pre-scaled by inv_sqrt_d=0.5),
// and the l<64 relative-bias delta table, from the current state sZ.
// Must be called by ALL threads of the block (contains barriers).
__device__ void compute_qar(const PParams& p, int tid,
                            float* sZ, float* sQ, float* sA, float* sRel) {
  if (tid < 32) {
    float acc = p.q_b[tid];
    const float* row = p.q_w + tid * 32;
    #pragma unroll
    for (int c = 0; c < 32; ++c) acc = fmaf(row[c], sZ[c], acc);
    sQ[tid] = acc;
  }
  __syncthreads();
  if (tid < 128) {
    int h = tid >> 5, c = tid & 31;
    float acc = 0.f;
    #pragma unroll
    for (int jj = 0; jj < 8; ++jj)
      acc = fmaf(sQ[8 * h + jj], p.k_w[(8 * h + jj) * 32 + c], acc);
    sA[tid] = 0.5f * acc;               // fold inv_sqrt_d
  }
  if (tid >= 256) {
    // rel-bias delta vs the saturated idx=128 entry (constant part cancels in softmax)
    int t = tid - 256;
    int l = t >> 2, h = t & 3;
    float acc = 0.f;
    #pragma unroll
    for (int jj = 0; jj < 8; ++jj) {
      int jidx = 8 * h + jj;
      acc = fmaf(sQ[jidx],
                 p.rel_bias[(l + 64) * 32 + jidx] - p.rel_bias[128 * 32 + jidx],
                 acc);
    }
    sRel[t] = 0.5f * acc;
  }
  __syncthreads();
}

// Minimal grid barrier: one release-add per block, relaxed spin on a flag,
// agent fences at the edges. Counters zeroed by hipMemsetAsync each launch.
__device__ __forceinline__ void grid_barrier(float* wsf, int iter, int tid) {
  unsigned* sync = reinterpret_cast<unsigned*>(wsf);
  __syncthreads();
  __threadfence();                     // release block's partial-table stores
  if (tid == 0) {
    unsigned* cnt = sync + 2 * iter;
    unsigned* flg = sync + 2 * iter + 1;
    unsigned old = __hip_atomic_fetch_add(cnt, 1u, __ATOMIC_RELEASE,
                                          __HIP_MEMORY_SCOPE_AGENT);
    if (old == (unsigned)(NB - 1)) {
      __hip_atomic_store(flg, 1u, __ATOMIC_RELEASE, __HIP_MEMORY_SCOPE_AGENT);
    } else {
      while (__hip_atomic_load(flg, __ATOMIC_RELAXED,
                               __HIP_MEMORY_SCOPE_AGENT) == 0u)
        __builtin_amdgcn_s_sleep(4);   // ~256-cycle poll granularity
    }
  }
  __syncthreads();
  __threadfence();                     // acquire: invalidate stale caches before reads
}

// One l-row contribution. Everything is SSA vectors / constant-indexed.
__device__ __forceinline__ void trip_body(const v8f (&A)[4], v8f zv,
                                          const float* sRel, bool dorel, int relrow,
                                          v8f (&S)[4], v4f& Zc) {
  float d0 = 0.f, d1 = 0.f, d2 = 0.f, d3 = 0.f;
  #pragma unroll
  for (int k = 0; k < 8; ++k) {
    d0 = fmaf(A[0][k], zv[k], d0);
    d1 = fmaf(A[1][k], zv[k], d1);
    d2 = fmaf(A[2][k], zv[k], d2);
    d3 = fmaf(A[3][k], zv[k], d3);
  }
  d0 += __shfl_xor(d0, 1); d0 += __shfl_xor(d0, 2);
  d1 += __shfl_xor(d1, 1); d1 += __shfl_xor(d1, 2);
  d2 += __shfl_xor(d2, 1); d2 += __shfl_xor(d2, 2);
  d3 += __shfl_xor(d3, 1); d3 += __shfl_xor(d3, 2);
  if (dorel) {
    const float4 r = reinterpret_cast<const float4*>(sRel)[relrow];
    d0 += r.x; d1 += r.y; d2 += r.z; d3 += r.w;
  }
  float w0 = __expf(d0), w1 = __expf(d1), w2 = __expf(d2), w3 = __expf(d3);
  Zc[0] += w0; Zc[1] += w1; Zc[2] += w2; Zc[3] += w3;
  S[0] += zv * w0;
  S[1] += zv * w1;
  S[2] += zv * w2;
  S[3] += zv * w3;
}

// Second launch-bounds arg = 1: evidence from rounds 1-2 shows it is applied as
// blocks/CU — a value of 2 produced a hard 128-VGPR cap (4 waves/EU) and
// spilled the 104-float z-slice to scratch. 1 block/CU -> 2 waves/EU -> 256 cap.
__global__ __launch_bounds__(BT, 1)
void photonic_kernel(PParams p) {
  __shared__ float sZ[32];
  __shared__ float sQ[32];
  __shared__ float sOutV[32];
  __shared__ float sZn[32];
  __shared__ __align__(32) float sA[128];     // a[h][c]
  __shared__ __align__(16) float sRel[256];   // relT[l][h], l<64
  __shared__ float sRed[BT / 64][4][36];      // per-wave reduced (S[4][8] + Z[4]) per quarter
  __shared__ float sSS[128];                  // global-reduced S[h][c]
  __shared__ float sSZ[4];                    // global-reduced Z[h]
  __shared__ __align__(16) float sZp[LDSROWS * LDSTRIDE];  // LDS-resident z rows (padded)

  const int tid  = threadIdx.x;
  const int b    = blockIdx.x;
  const int j    = tid & 3;        // quarter (owns columns [8j, 8j+8))
  const int quad = tid >> 2;       // 0..127
  const int wave = tid >> 6;
  const int lane = tid & 63;

  const int chunk0 = b * CHUNK;
  const int clen   = min(CHUNK, p.L - chunk0);          // 1954, last block 1730
  const int ldsl   = min(clen - REGL, (int)LDSROWS);    // 290, last block 66

  // init state z = candidate (real-interleaved flat 32)
  if (tid < 32) sZ[tid] = p.candidate[tid];
  __syncthreads();
  compute_qar(p, tid, sZ, sQ, sA, sRel);

  // Register-resident slice of z_past: rows chunk0 + quad + t*128, t < REGT.
  v8f zr0, zr1, zr2, zr3, zr4, zr5, zr6, zr7, zr8, zr9, zr10, zr11, zr12;

  for (int iter = 0; iter < MSTEPS; ++iter) {
    // stage my quarter of a[h][*] into registers
    v8f A[4];
    #pragma unroll
    for (int h = 0; h < 4; ++h)
      A[h] = *reinterpret_cast<const v8f*>(sA + h * 32 + j * 8);

    v8f S[4];
    #pragma unroll
    for (int h = 0; h < 4; ++h) S[h] = 0.f;
    v4f Zc = 0.f;

    if (iter == 0) {
      // ---- first pass: load from HBM, populate registers + LDS, and compute ----
      #define LOADROW(t, dst)                                                   \
        {                                                                       \
          dst = *reinterpret_cast<const v8f*>(                                  \
              p.z_past + (size_t)(chunk0 + quad + ((t) << 7)) * 32 + j * 8);    \
          trip_body(A, dst, sRel, (b == 0) && ((t) == 0) && (quad < 64), quad,  \
                    S, Zc);                                                     \
        }
      LOADROW(0, zr0)  LOADROW(1, zr1)  LOADROW(2, zr2)  LOADROW(3, zr3)
      LOADROW(4, zr4)  LOADROW(5, zr5)  LOADROW(6, zr6)  LOADROW(7, zr7)
      LOADROW(8, zr8)  LOADROW(9, zr9)  LOADROW(10, zr10) LOADROW(11, zr11)
      LOADROW(12, zr12)
      #undef LOADROW
      #pragma unroll
      for (int t = 0; t < 3; ++t) {
        int li = quad + (t << 7);
        if (li < ldsl) {
          v8f zv = *reinterpret_cast<const v8f*>(
              p.z_past + (size_t)(chunk0 + REGL + li) * 32 + j * 8);
          float* dst = sZp + li * LDSTRIDE + j * 8;
          *reinterpret_cast<v4f*>(dst)     = __builtin_shufflevector(zv, zv, 0, 1, 2, 3);
          *reinterpret_cast<v4f*>(dst + 4) = __builtin_shufflevector(zv, zv, 4, 5, 6, 7);
          trip_body(A, zv, sRel, false, 0, S, Zc);
        }
      }
    } else {
      // ---- steady state: zero global traffic; registers + LDS only ----
      #define COMPROW(t, src)                                                   \
        trip_body(A, src, sRel, (b == 0) && ((t) == 0) && (quad < 64), quad, S, \
                  Zc);
      COMPROW(0, zr0)  COMPROW(1, zr1)  COMPROW(2, zr2)  COMPROW(3, zr3)
      COMPROW(4, zr4)  COMPROW(5, zr5)  COMPROW(6, zr6)  COMPROW(7, zr7)
      COMPROW(8, zr8)  COMPROW(9, zr9)  COMPROW(10, zr10) COMPROW(11, zr11)
      COMPROW(12, zr12)
      #undef COMPROW
      #pragma unroll
      for (int t = 0; t < 3; ++t) {
        int li = quad + (t << 7);
        if (li < ldsl) {
          const float* src = sZp + li * LDSTRIDE + j * 8;
          v4f a4 = *reinterpret_cast<const v4f*>(src);
          v4f b4 = *reinterpret_cast<const v4f*>(src + 4);
          v8f zv = __builtin_shufflevector(a4, b4, 0, 1, 2, 3, 4, 5, 6, 7);
          trip_body(A, zv, sRel, false, 0, S, Zc);
        }
      }
    }

    // reduce across the 16 quads of each wave (lane%4 == quarter is preserved)
    #pragma unroll
    for (int m = 4; m <= 32; m <<= 1) {
      #pragma unroll
      for (int h = 0; h < 4; ++h) {
        #pragma unroll
        for (int k = 0; k < 8; ++k) S[h][k] += __shfl_xor(S[h][k], m);
        Zc[h] += __shfl_xor(Zc[h], m);
      }
    }
    if ((lane >> 2) == 0) {  // lanes 0..3: lane == quarter j
      #pragma unroll
      for (int h = 0; h < 4; ++h) {
        #pragma unroll
        for (int k = 0; k < 8; ++k) sRed[wave][lane][h * 8 + k] = S[h][k];
        sRed[wave][lane][32 + h] = Zc[h];
      }
    }
    __syncthreads();

    // per-block partials -> global, component-major [comp][block] for coalesced reduce
    float* part = p.ws + 16 + (iter & 1) * (132 * NB);
    if (tid < 132) {
      float acc = 0.f;
      if (tid < 128) {
        int h = tid >> 5, c = tid & 31;
        int jj = c >> 3, k = c & 7;
        #pragma unroll
        for (int w2 = 0; w2 < BT / 64; ++w2) acc += sRed[w2][jj][h * 8 + k];
        part[(h * 33 + c) * NB + b] = acc;
      } else {
        int h = tid - 128;
        #pragma unroll
        for (int w2 = 0; w2 < BT / 64; ++w2) acc += sRed[w2][0][32 + h];
        part[(h * 33 + 32) * NB + b] = acc;
      }
    }

    grid_barrier(p.ws, iter, tid);

    // every block redundantly reduces all partials (135 KB, L2/L3-resident)
    if (tid < 132) {
      const float4* pp = reinterpret_cast<const float4*>(part + tid * NB);
      float acc = 0.f;
      for (int i = 0; i < NB / 4; ++i) {
        float4 v4 = pp[i];
        acc += (v4.x + v4.y) + (v4.z + v4.w);
      }
      int h = tid / 33, k = tid % 33;
      if (k < 32) sSS[h * 32 + k] = acc; else sSZ[h] = acc;
    }
    __syncthreads();

    // out_flat[j'] = v_w[j',:] @ (S_h / Z_h) + v_b[j']   (h = j'>>3)
    if (tid < 32) {
      int h = tid >> 3;
      float acc = 0.f;
      const float* row = p.v_w + tid * 32;
      #pragma unroll
      for (int c = 0; c < 32; ++c) acc = fmaf(row[c], sSS[h * 32 + c], acc);
      sOutV[tid] = acc / sSZ[h] + p.v_b[tid];
    }
    __syncthreads();
    // mod = o_w @ out + o_b ; z += coupling*mod ; mish
    if (tid < 32) {
      float acc = p.o_b[tid];
      const float* row = p.o_w + tid * 32;
      #pragma unroll
      for (int c = 0; c < 32; ++c) acc = fmaf(row[c], sOutV[c], acc);
      float zv2 = sZ[tid] + p.coupling[0] * acc;
      sZn[tid] = mish_f(zv2);
    }
    __syncthreads();
    // layer-norm over the 16 real / 16 imag components separately
    if (tid < 32) {
      int par = tid & 1;
      float m = 0.f;
      #pragma unroll
      for (int e = 0; e < 16; ++e) m += sZn[2 * e + par];
      m *= (1.f / 16.f);
      float v = 0.f;
      #pragma unroll
      for (int e = 0; e < 16; ++e) { float dd = sZn[2 * e + par] - m; v = fmaf(dd, dd, v); }
      v *= (1.f / 16.f);
      sZ[tid] = (sZn[tid] - m) * rsqrtf(v + 1e-5f) * p.norm_scale[0];
    }
    __syncthreads();

    if (iter != MSTEPS - 1) {
      compute_qar(p, tid, sZ, sQ, sA, sRel);
    } else {
      if (b == 0 && tid < 32) p.out[tid] = sZ[tid];
    }
  }
}

extern "C" void kernel_launch(void* const* d_in, const int* in_sizes, int n_in,
                              void* d_out, int out_size, void* d_ws, size_t ws_size,
                              hipStream_t stream) {
  PParams p;
  p.candidate  = (const float*)d_in[0];
  p.z_past     = (const float*)d_in[1];
  p.q_w = (const float*)d_in[2];  p.q_b = (const float*)d_in[3];
  p.k_w = (const float*)d_in[4];  p.k_b = (const float*)d_in[5];
  p.v_w = (const float*)d_in[6];  p.v_b = (const float*)d_in[7];
  p.o_w = (const float*)d_in[8];  p.o_b = (const float*)d_in[9];
  p.rel_bias   = (const float*)d_in[10];
  p.coupling   = (const float*)d_in[11];
  p.norm_scale = (const float*)d_in[12];
  p.out = (float*)d_out;
  p.ws  = (float*)d_ws;
  p.L   = in_sizes[1] / 32;

  // zero the 16 barrier words (captured as a graph node -> re-zeroed every replay)
  hipMemsetAsync(d_ws, 0, 64, stream);

  void* args[] = { &p };
  hipLaunchCooperativeKernel((const void*)photonic_kernel,
                             dim3(NB), dim3(BT), args, 0, stream);
}